// Round 10
// baseline (278.789 us; speedup 1.0000x reference)
//
#include <hip/hip_runtime.h>
#include <hip/hip_bf16.h>

typedef __attribute__((ext_vector_type(8))) short short8;
typedef __attribute__((ext_vector_type(4))) float f32x4;

#define NGRAPHS 1024
#define D_DIM 512
#define H_DIM 128
#define BM 64    // rows per tile
#define PBLK 256 // persistent blocks (1 per CU; 130KB LDS)

// standard RNE f32->bf16 pair pack; compiler lowers to v_cvt_pk_bf16_f32
static __device__ __forceinline__ unsigned int pack_bf2(float a, float b) {
    float2 t; t.x = a; t.y = b;
    __hip_bfloat162 h = __float22bfloat162_rn(t);
    union { __hip_bfloat162 h; unsigned int u; } v;
    v.h = h;
    return v.u;
}

static __device__ __forceinline__ unsigned short f2bf(float f) {
    __hip_bfloat16 h = __float2bfloat16(f);
    union { __hip_bfloat16 h; unsigned short u; } v;
    v.h = h;
    return v.u;
}

static __device__ __forceinline__ float fast_tanh(float x) {
    float cx = fminf(fmaxf(x, -15.f), 15.f);
    float e = __expf(2.f * cx);
    return (e - 1.f) / (e + 1.f);
}

// ---------------- segment offsets via binary search ----------------
__global__ void seg_offsets_kernel(const int* __restrict__ batch, int N,
                                   int* __restrict__ off) {
    int g = blockIdx.x * 256 + threadIdx.x;
    if (g > NGRAPHS) return;
    int lo = 0, hi = N;
    while (lo < hi) {
        int mid = (lo + hi) >> 1;
        if (batch[mid] < g) lo = mid + 1;
        else hi = mid;
    }
    off[g] = lo;
}

// ---- W1 [512][128] f32 -> fragment-major bf16 W1TF ----
// W1TF[cgrp][ki][lane][e]: col = cgrp*16 + (lane&15), k = ki*32 + (lane>>4)*8 + e.
__global__ void prep_w1t_kernel(const float* __restrict__ W1,
                                unsigned short* __restrict__ W1TF) {
    int idx = blockIdx.x * 256 + threadIdx.x;  // 0..65535
    int e = idx & 7;
    int lane = (idx >> 3) & 63;
    int ki = (idx >> 9) & 15;
    int cgrp = idx >> 13;  // 0..7
    int col = cgrp * 16 + (lane & 15);
    int k = ki * 32 + (lane >> 4) * 8 + e;
    W1TF[idx] = f2bf(W1[k * H_DIM + col]);
}

// ---- staging helpers: 128 (row,half) 1KB tasks, 16 per thread ----
static __device__ __forceinline__ void stage_issue(const float* __restrict__ h,
                                                   int N, int t, int w, int lane,
                                                   float4* f) {
#pragma unroll
    for (int i = 0; i < 16; ++i) {
        const int task = i * 8 + w;
        const int row = task >> 1, half = task & 1;
        int gr = t * BM + row;
        gr = gr < N ? gr : N - 1;
        f[i] = *(const float4*)(h + (size_t)gr * D_DIM + half * 256 + lane * 4);
    }
}

static __device__ __forceinline__ void stage_commit(unsigned short* __restrict__ buf,
                                                    int w, int lane,
                                                    const float4* f) {
#pragma unroll
    for (int i = 0; i < 16; ++i) {
        const int task = i * 8 + w;
        const int row = task >> 1, half = task & 1;
        const int unit = half * 32 + (lane >> 1);
        uint2 v;
        v.x = pack_bf2(f[i].x, f[i].y);
        v.y = pack_bf2(f[i].z, f[i].w);
        *(uint2*)&buf[row * D_DIM + ((unit ^ (row & 7)) * 8) + (lane & 1) * 4] = v;
    }
}

// =================== persistent double-buffered main kernel ===================
// 512 threads (8 waves); wave w owns gate cols [w*16,w*16+16). exp() without
// max-subtraction is safe (|logit| <= ||W2||_1 ~ 9; b2 cancels in softmax).
// Per tile: <=2 boundary partial records P[t][slot][513]; interior graphs
// final-written directly. reduce_kernel combines boundary partials.
__global__ __launch_bounds__(512, 2) void gate_pool_persist_kernel(
    const float* __restrict__ h, const unsigned short* __restrict__ W1TF,
    const float* __restrict__ b1, const float* __restrict__ W2,
    const int* __restrict__ batch, float* __restrict__ P,
    float* __restrict__ out, int N, int NT) {
    __shared__ unsigned short hA[2][BM * D_DIM];  // 128 KB double buffer
    __shared__ float plds[8][BM];
    __shared__ float wl[BM];
    __shared__ int gb[BM];

    const int tid = threadIdx.x;
    const int lane = tid & 63;
    const int w = tid >> 6;
    const int cg = lane & 15;
    const int qg = lane >> 4;

    // B fragments: loaded ONCE per block lifetime (L2-hot)
    short8 bfr[16];
#pragma unroll
    for (int ki = 0; ki < 16; ++ki)
        bfr[ki] = *(const short8*)(W1TF + ((w * 16 + ki) << 9) + lane * 8);

    const float b1v = b1[w * 16 + cg];
    const float w2v = W2[w * 16 + cg];
    const int d0 = (tid >> 2) * 8 + (tid & 3) * 2;

    int t = blockIdx.x;
    if (t >= NT) return;
    {   // prologue: stage tile t into buf 0
        float4 f[16];
        stage_issue(h, N, t, w, lane, f);
        stage_commit(&hA[0][0], w, lane, f);
    }
    __syncthreads();

    int cur = 0;
    for (;;) {
        if (tid < BM) {
            int gr = t * BM + tid;
            gb[tid] = batch[gr < N ? gr : N - 1];
        }
        const int tn = t + PBLK;
        const bool have = tn < NT;
        float4 pf[16];
        if (have) stage_issue(h, N, tn, w, lane, pf);
        __builtin_amdgcn_sched_barrier(0);  // pin prefetch issue before compute

        // ---- gate MLP on buf[cur]: 64 rows x 16 cols/wave, K=512 ----
        f32x4 acc[4];
#pragma unroll
        for (int rf = 0; rf < 4; ++rf) acc[rf] = (f32x4){0.f, 0.f, 0.f, 0.f};
#pragma unroll
        for (int ki = 0; ki < 16; ++ki) {
#pragma unroll
            for (int rf = 0; rf < 4; ++rf) {
                const short8 af = *(const short8*)&hA[cur][(rf * 16 + cg) * D_DIM +
                    (((4 * ki + qg) ^ (cg & 7)) * 8)];
                acc[rf] = __builtin_amdgcn_mfma_f32_16x16x32_bf16(af, bfr[ki],
                                                                  acc[rf], 0, 0, 0);
            }
        }

        // ---- epilogue: per-row partial logit over this wave's 16 cols ----
#pragma unroll
        for (int rf = 0; rf < 4; ++rf) {
#pragma unroll
            for (int reg = 0; reg < 4; ++reg) {
                float p = fast_tanh(acc[rf][reg] + b1v) * w2v;
#pragma unroll
                for (int o = 1; o < 16; o <<= 1) p += __shfl_xor(p, o, 64);
                if (cg == 0) plds[w][rf * 16 + qg * 4 + reg] = p;
            }
        }
        __syncthreads();  // plds + gb visible

        if (tid < BM) {
            float l = plds[0][tid] + plds[1][tid] + plds[2][tid] + plds[3][tid] +
                      plds[4][tid] + plds[5][tid] + plds[6][tid] + plds[7][tid];
            wl[tid] = (t * BM + tid < N) ? __expf(fminf(l, 60.f)) : 0.f;
        }
        __syncthreads();  // wl visible

        // ---- pooling + segment flushes (threads 0..255, 2 dims each) ----
        if (tid < 256) {
            float ax = 0.f, ay = 0.f, d = 0.f;
            int curg = gb[0];
#pragma unroll 8
            for (int j = 0; j < BM; ++j) {
                const int gj = gb[j];
                if (gj != curg) {  // block-uniform branch
                    if (curg == gb[0]) {
                        float* rec = P + (size_t)t * 2 * 513;
                        rec[d0] = ax; rec[d0 + 1] = ay;
                        if (tid == 0) rec[512] = d;
                    } else {  // interior graph: exclusive owner -> final write
                        out[(size_t)curg * D_DIM + d0] = ax / d;
                        out[(size_t)curg * D_DIM + d0 + 1] = ay / d;
                    }
                    ax = 0.f; ay = 0.f; d = 0.f; curg = gj;
                }
                const float wj = wl[j];
                const unsigned int pair = *(const unsigned int*)&hA[cur][j * D_DIM +
                    (((tid >> 2) ^ (j & 7)) * 8) + (tid & 3) * 2];
                ax += wj * __uint_as_float(pair << 16);
                ay += wj * __uint_as_float(pair & 0xffff0000u);
                d += wj;
            }
            const int slot = (curg == gb[0]) ? 0 : 1;
            float* rec = P + ((size_t)t * 2 + slot) * 513;
            rec[d0] = ax; rec[d0 + 1] = ay;
            if (tid == 0) rec[512] = d;
            if (gb[0] == gb[BM - 1]) {  // slot1 unused -> zero for determinism
                float* r1 = P + ((size_t)t * 2 + 1) * 513;
                r1[d0] = 0.f; r1[d0 + 1] = 0.f;
                if (tid == 0) r1[512] = 0.f;
            }
        }

        // ---- commit prefetched tile into the other buffer ----
        if (have) stage_commit(&hA[cur ^ 1][0], w, lane, pf);
        __syncthreads();
        if (!have) break;
        t = tn;
        cur ^= 1;
    }
}

// combine boundary partials; skip interior graphs (already final-written)
__global__ __launch_bounds__(512) void reduce_kernel(
    const float* __restrict__ P, const int* __restrict__ off,
    const int* __restrict__ batch, float* __restrict__ out, int N) {
    const int g = blockIdx.x;
    const int tid = threadIdx.x;
    const int s = off[g], e = off[g + 1];
    if (e <= s) { out[(size_t)g * D_DIM + tid] = 0.f; return; }
    const int t0 = s >> 6, t1 = (e - 1) >> 6;
    float sum = 0.f, den = 0.f;
    bool found = false;
    for (int b = t0; b <= t1; ++b) {
        const int fg = batch[b << 6];
        const int le = (b << 6) + 63;
        const int lg = batch[le < N ? le : N - 1];
        if (fg == g) {
            const float* rec = P + (size_t)b * 2 * 513;
            sum += rec[tid]; den += rec[512]; found = true;
        } else if (lg == g) {
            const float* rec = P + ((size_t)b * 2 + 1) * 513;
            sum += rec[tid]; den += rec[512]; found = true;
        }
    }
    if (found) out[(size_t)g * D_DIM + tid] = sum / den;
}

// =================== ATOMIC FALLBACK (R8/R9, proven) ===================
__global__ void zero_kernel(float* __restrict__ out, float* __restrict__ den) {
    int i = blockIdx.x * 256 + threadIdx.x;
    if (i < NGRAPHS * D_DIM) out[i] = 0.f;
    if (i < NGRAPHS) den[i] = 0.f;
}

__global__ __launch_bounds__(256) void gate_pool_atomic_kernel(
    const float* __restrict__ h, const unsigned short* __restrict__ W1TF,
    const float* __restrict__ b1, const float* __restrict__ W2,
    const int* __restrict__ batch, float* __restrict__ outnum,
    float* __restrict__ den, int N) {
    __shared__ unsigned short hA[BM * D_DIM];
    __shared__ float plds[4][BM];
    __shared__ float wl[BM];
    __shared__ int gb[BM];

    const int tid = threadIdx.x;
    const int lane = tid & 63;
    const int w = tid >> 6;
    const int cg = lane & 15;
    const int qg = lane >> 4;
    const int row0 = blockIdx.x * BM;

    if (tid < BM) {
        int gr = row0 + tid;
        gb[tid] = batch[gr < N ? gr : N - 1];
    }
#pragma unroll
    for (int b = 0; b < 4; ++b) {
        float4 fa[4], fb[4];
#pragma unroll
        for (int i = 0; i < 4; ++i) {
            const int fi = (b * 4 + i) * 256 + tid;
            const int r = fi >> 6, u = fi & 63;
            int gr = row0 + r;
            gr = gr < N ? gr : N - 1;
            const float* p = h + (size_t)gr * D_DIM + u * 8;
            fa[i] = *(const float4*)p;
            fb[i] = *(const float4*)(p + 4);
        }
#pragma unroll
        for (int i = 0; i < 4; ++i) {
            const int fi = (b * 4 + i) * 256 + tid;
            const int r = fi >> 6, u = fi & 63;
            uint4 val;
            val.x = pack_bf2(fa[i].x, fa[i].y);
            val.y = pack_bf2(fa[i].z, fa[i].w);
            val.z = pack_bf2(fb[i].x, fb[i].y);
            val.w = pack_bf2(fb[i].z, fb[i].w);
            *(uint4*)&hA[r * D_DIM + ((u ^ (r & 7)) * 8)] = val;
        }
    }
    __syncthreads();

    f32x4 acc[4][2];
#pragma unroll
    for (int rf = 0; rf < 4; ++rf)
#pragma unroll
        for (int cf = 0; cf < 2; ++cf) acc[rf][cf] = (f32x4){0.f, 0.f, 0.f, 0.f};
#pragma unroll
    for (int ki = 0; ki < 16; ++ki) {
        short8 bfg[2];
#pragma unroll
        for (int cf = 0; cf < 2; ++cf)
            bfg[cf] = *(const short8*)(W1TF + (((w * 2 + cf) * 16 + ki) << 9) + lane * 8);
#pragma unroll
        for (int rf = 0; rf < 4; ++rf) {
            const int row = rf * 16 + cg;
            const short8 af = *(const short8*)&hA[row * D_DIM +
                (((4 * ki + qg) ^ (row & 7)) * 8)];
#pragma unroll
            for (int cf = 0; cf < 2; ++cf)
                acc[rf][cf] = __builtin_amdgcn_mfma_f32_16x16x32_bf16(
                    af, bfg[cf], acc[rf][cf], 0, 0, 0);
        }
    }
    const float b1v0 = b1[w * 32 + cg];
    const float b1v1 = b1[w * 32 + 16 + cg];
    const float w2v0 = W2[w * 32 + cg];
    const float w2v1 = W2[w * 32 + 16 + cg];
#pragma unroll
    for (int rf = 0; rf < 4; ++rf) {
#pragma unroll
        for (int reg = 0; reg < 4; ++reg) {
            float p = fast_tanh(acc[rf][0][reg] + b1v0) * w2v0 +
                      fast_tanh(acc[rf][1][reg] + b1v1) * w2v1;
#pragma unroll
            for (int o = 1; o < 16; o <<= 1) p += __shfl_xor(p, o, 64);
            if (cg == 0) plds[w][rf * 16 + qg * 4 + reg] = p;
        }
    }
    __syncthreads();
    if (tid < BM) {
        const float l = plds[0][tid] + plds[1][tid] + plds[2][tid] + plds[3][tid];
        wl[tid] = (row0 + tid < N) ? __expf(fminf(l, 60.f)) : 0.f;
    }
    __syncthreads();

    const int d0 = (tid >> 2) * 8 + (tid & 3) * 2;
    float ax = 0.f, ay = 0.f;
    int cur = gb[0];
#pragma unroll 8
    for (int j = 0; j < BM; ++j) {
        const int gj = gb[j];
        if (gj != cur) {
            atomicAdd(&outnum[(size_t)cur * D_DIM + d0], ax);
            atomicAdd(&outnum[(size_t)cur * D_DIM + d0 + 1], ay);
            ax = 0.f; ay = 0.f; cur = gj;
        }
        const float wj = wl[j];
        const unsigned int pair = *(const unsigned int*)&hA[j * D_DIM +
            (((tid >> 2) ^ (j & 7)) * 8) + (tid & 3) * 2];
        ax += wj * __uint_as_float(pair << 16);
        ay += wj * __uint_as_float(pair & 0xffff0000u);
    }
    atomicAdd(&outnum[(size_t)cur * D_DIM + d0], ax);
    atomicAdd(&outnum[(size_t)cur * D_DIM + d0 + 1], ay);

    if (tid == 0) {
        float a = 0.f;
        int c2 = gb[0];
        for (int j = 0; j < BM; ++j) {
            if (gb[j] != c2) { atomicAdd(&den[c2], a); a = 0.f; c2 = gb[j]; }
            a += wl[j];
        }
        atomicAdd(&den[c2], a);
    }
}

__global__ __launch_bounds__(512) void finalize_kernel(
    float* __restrict__ out, const float* __restrict__ den) {
    const int g = blockIdx.x;
    const float dv = den[g];
    const float v = out[(size_t)g * D_DIM + threadIdx.x];
    out[(size_t)g * D_DIM + threadIdx.x] = dv > 0.f ? v / dv : 0.f;
}

extern "C" void kernel_launch(void* const* d_in, const int* in_sizes, int n_in,
                              void* d_out, int out_size, void* d_ws, size_t ws_size,
                              hipStream_t stream) {
    const float* h = (const float*)d_in[0];
    const int* batch = (const int*)d_in[1];
    const float* W1 = (const float*)d_in[2];
    const float* b1 = (const float*)d_in[3];
    const float* W2 = (const float*)d_in[4];
    // b2 unused: constant shift cancels in segment softmax
    float* out = (float*)d_out;
    const int N = in_sizes[1];
    const int NT = (N + BM - 1) / BM;

    char* ws = (char*)d_ws;
    int* off = (int*)ws;                                  // 4100 B
    unsigned short* W1TF = (unsigned short*)(ws + 4608);  // 131072 B
    float* P = (float*)(ws + 135680);                     // NT*2*513 floats

    const size_t need = 135680 + (size_t)NT * 2 * 513 * 4;

    seg_offsets_kernel<<<(NGRAPHS + 256) / 256 + 1, 256, 0, stream>>>(batch, N, off);
    prep_w1t_kernel<<<(D_DIM * H_DIM) / 256, 256, 0, stream>>>(W1, W1TF);

    if (ws_size >= need) {
        gate_pool_persist_kernel<<<PBLK, 512, 0, stream>>>(h, W1TF, b1, W2, batch,
                                                           P, out, N, NT);
        reduce_kernel<<<NGRAPHS, 512, 0, stream>>>(P, off, batch, out, N);
    } else {
        float* den = P;  // 4 KB
        zero_kernel<<<(NGRAPHS * D_DIM + 255) / 256, 256, 0, stream>>>(out, den);
        gate_pool_atomic_kernel<<<NT, 256, 0, stream>>>(h, W1TF, b1, W2, batch,
                                                        out, den, N);
        finalize_kernel<<<NGRAPHS, 512, 0, stream>>>(out, den);
    }
}

// Round 11
// 155.618 us; speedup vs baseline: 1.7915x; 1.7915x over previous
//
#include <hip/hip_runtime.h>
#include <hip/hip_bf16.h>

typedef __attribute__((ext_vector_type(8))) short short8;
typedef __attribute__((ext_vector_type(4))) float f32x4;

#define NGRAPHS 1024
#define D_DIM 512
#define H_DIM 128
#define BM 64  // rows per block

// standard RNE f32->bf16 pair pack; compiler lowers to v_cvt_pk_bf16_f32
static __device__ __forceinline__ unsigned int pack_bf2(float a, float b) {
    float2 t; t.x = a; t.y = b;
    __hip_bfloat162 h = __float22bfloat162_rn(t);
    union { __hip_bfloat162 h; unsigned int u; } v;
    v.h = h;
    return v.u;
}

static __device__ __forceinline__ unsigned short f2bf(float f) {
    __hip_bfloat16 h = __float2bfloat16(f);
    union { __hip_bfloat16 h; unsigned short u; } v;
    v.h = h;
    return v.u;
}

static __device__ __forceinline__ float fast_tanh(float x) {
    float cx = fminf(fmaxf(x, -15.f), 15.f);
    float e = __expf(2.f * cx);
    return (e - 1.f) / (e + 1.f);
}

// ---------------- segment offsets via binary search ----------------
__global__ void seg_offsets_kernel(const int* __restrict__ batch, int N,
                                   int* __restrict__ off) {
    int g = blockIdx.x * 256 + threadIdx.x;
    if (g > NGRAPHS) return;
    int lo = 0, hi = N;
    while (lo < hi) {
        int mid = (lo + hi) >> 1;
        if (batch[mid] < g) lo = mid + 1;
        else hi = mid;
    }
    off[g] = lo;
}

// ---- W1 [512][128] f32 -> fragment-major bf16 W1TF ----
// W1TF[cgrp][ki][lane][e]: col = cgrp*16 + (lane&15), k = ki*32 + (lane>>4)*8 + e.
__global__ void prep_w1t_kernel(const float* __restrict__ W1,
                                unsigned short* __restrict__ W1TF) {
    int idx = blockIdx.x * 256 + threadIdx.x;  // 0..65535
    int e = idx & 7;
    int lane = (idx >> 3) & 63;
    int ki = (idx >> 9) & 15;
    int cgrp = idx >> 13;  // 0..7
    int col = cgrp * 16 + (lane & 15);
    int k = ki * 32 + (lane >> 4) * 8 + e;
    W1TF[idx] = f2bf(W1[k * H_DIM + col]);
}

// =================== PARTIAL-STORE PATH (no atomics) ===================
// 512 threads (8 waves), 64 rows/block. Wave w owns gate cols [w*16,w*16+16).
// exp() without max-subtraction is safe: |logit| <= ||W2||_1 ~ 9; b2 cancels.
// Each block writes <=2 boundary partial records P[b][slot][513] (512 num + den);
// interior graphs are final-written directly. reduce_kernel combines partials.
// VGPR budget: stage f[16]=64 live only BEFORE bfr loads; MFMA phase bfr 64 +
// acc 16 -> peak < 128 (16 waves/CU, 2 blocks co-resident).
__global__ __launch_bounds__(512) void gate_pool_partial_kernel(
    const float* __restrict__ h, const unsigned short* __restrict__ W1TF,
    const float* __restrict__ b1, const float* __restrict__ W2,
    const int* __restrict__ batch, float* __restrict__ P,
    float* __restrict__ out, int N) {
    __shared__ unsigned short hA[BM * D_DIM];  // 64 KB, XOR-swizzled 16B units
    __shared__ float plds[8][BM];
    __shared__ float wl[BM];
    __shared__ int gb[BM];

    const int tid = threadIdx.x;
    const int lane = tid & 63;
    const int w = tid >> 6;
    const int cg = lane & 15;
    const int qg = lane >> 4;
    const int row0 = blockIdx.x * BM;

    if (tid < BM) {
        int gr = row0 + tid;
        gb[tid] = batch[gr < N ? gr : N - 1];
    }

    // ---- stage h -> bf16 LDS. 128 (row,half) 1KB tasks, 16 per thread.
    // All 16 loads issued BEFORE any commit: one HBM latency, 15 amortized.
    {
        float4 f[16];
#pragma unroll
        for (int i = 0; i < 16; ++i) {
            const int task = i * 8 + w;
            const int row = task >> 1, half = task & 1;
            int gr = row0 + row;
            gr = gr < N ? gr : N - 1;
            f[i] = *(const float4*)(h + (size_t)gr * D_DIM + half * 256 + lane * 4);
        }
        __builtin_amdgcn_sched_barrier(0);  // keep all loads above the packs
#pragma unroll
        for (int i = 0; i < 16; ++i) {
            const int task = i * 8 + w;
            const int row = task >> 1, half = task & 1;
            const int unit = half * 32 + (lane >> 1);
            uint2 v;
            v.x = pack_bf2(f[i].x, f[i].y);
            v.y = pack_bf2(f[i].z, f[i].w);
            *(uint2*)&hA[row * D_DIM + ((unit ^ (row & 7)) * 8) + (lane & 1) * 4] = v;
        }
    }

    // B fragments into registers while waiting at the barrier (L2-hot)
    short8 bfr[16];
#pragma unroll
    for (int ki = 0; ki < 16; ++ki)
        bfr[ki] = *(const short8*)(W1TF + ((w * 16 + ki) << 9) + lane * 8);
    __syncthreads();

    // ---- gate MLP: 64 rows x 16 cols per wave, K=512 ----
    f32x4 acc[4];
#pragma unroll
    for (int rf = 0; rf < 4; ++rf) acc[rf] = (f32x4){0.f, 0.f, 0.f, 0.f};
#pragma unroll
    for (int ki = 0; ki < 16; ++ki) {
#pragma unroll
        for (int rf = 0; rf < 4; ++rf) {
            const short8 af = *(const short8*)&hA[(rf * 16 + cg) * D_DIM +
                (((4 * ki + qg) ^ (cg & 7)) * 8)];
            acc[rf] = __builtin_amdgcn_mfma_f32_16x16x32_bf16(af, bfr[ki],
                                                              acc[rf], 0, 0, 0);
        }
    }

    // ---- epilogue: per-row partial logit over this wave's 16 cols ----
    const float b1v = b1[w * 16 + cg];
    const float w2v = W2[w * 16 + cg];
#pragma unroll
    for (int rf = 0; rf < 4; ++rf) {
#pragma unroll
        for (int reg = 0; reg < 4; ++reg) {
            float p = fast_tanh(acc[rf][reg] + b1v) * w2v;
#pragma unroll
            for (int o = 1; o < 16; o <<= 1) p += __shfl_xor(p, o, 64);
            if (cg == 0) plds[w][rf * 16 + qg * 4 + reg] = p;
        }
    }
    __syncthreads();

    if (tid < BM) {
        float l = plds[0][tid] + plds[1][tid] + plds[2][tid] + plds[3][tid] +
                  plds[4][tid] + plds[5][tid] + plds[6][tid] + plds[7][tid];
        wl[tid] = (row0 + tid < N) ? __expf(fminf(l, 60.f)) : 0.f;
    }
    __syncthreads();

    // ---- pooling + segment flushes: ALL 512 threads, thread owns dim tid ----
    {
        const int unit0 = tid >> 3;  // dim's 16B unit
        const int e = tid & 7;       // elem within unit
        float ax = 0.f, d = 0.f;
        int curg = gb[0];
#pragma unroll 8
        for (int j = 0; j < BM; ++j) {
            const int gj = gb[j];
            if (gj != curg) {  // block-uniform branch
                if (curg == gb[0]) {
                    float* rec = P + (size_t)blockIdx.x * 2 * 513;
                    rec[tid] = ax;
                    if (tid == 0) rec[512] = d;
                } else {  // interior graph: exclusive owner -> final write
                    out[(size_t)curg * D_DIM + tid] = ax / d;
                }
                ax = 0.f; d = 0.f; curg = gj;
            }
            const float wj = wl[j];
            const unsigned short us =
                hA[j * D_DIM + ((unit0 ^ (j & 7)) * 8) + e];
            ax += wj * __uint_as_float(((unsigned int)us) << 16);
            d += wj;
        }
        // final flush: curg == gb[63]; slot0 if it's also the first graph
        {
            const int slot = (curg == gb[0]) ? 0 : 1;
            float* rec = P + ((size_t)blockIdx.x * 2 + slot) * 513;
            rec[tid] = ax;
            if (tid == 0) rec[512] = d;
        }
        if (gb[0] == gb[BM - 1]) {  // slot1 unused -> zero for determinism
            float* r1 = P + ((size_t)blockIdx.x * 2 + 1) * 513;
            r1[tid] = 0.f;
            if (tid == 0) r1[512] = 0.f;
        }
    }
}

// combine boundary partials; skip interior graphs (already final-written)
__global__ __launch_bounds__(512) void reduce_kernel(
    const float* __restrict__ P, const int* __restrict__ off,
    const int* __restrict__ batch, float* __restrict__ out, int N) {
    const int g = blockIdx.x;
    const int tid = threadIdx.x;
    const int s = off[g], e = off[g + 1];
    if (e <= s) { out[(size_t)g * D_DIM + tid] = 0.f; return; }
    const int t0 = s >> 6, t1 = (e - 1) >> 6;
    float sum = 0.f, den = 0.f;
    bool found = false;
    for (int b = t0; b <= t1; ++b) {
        const int fg = batch[b << 6];
        const int le = (b << 6) + 63;
        const int lg = batch[le < N ? le : N - 1];
        if (fg == g) {
            const float* rec = P + (size_t)b * 2 * 513;
            sum += rec[tid]; den += rec[512]; found = true;
        } else if (lg == g) {
            const float* rec = P + ((size_t)b * 2 + 1) * 513;
            sum += rec[tid]; den += rec[512]; found = true;
        }
    }
    if (found) out[(size_t)g * D_DIM + tid] = sum / den;
}

// =================== ATOMIC FALLBACK (R8/R9, proven) ===================
__global__ void zero_kernel(float* __restrict__ out, float* __restrict__ den) {
    int i = blockIdx.x * 256 + threadIdx.x;
    if (i < NGRAPHS * D_DIM) out[i] = 0.f;
    if (i < NGRAPHS) den[i] = 0.f;
}

__global__ __launch_bounds__(256) void gate_pool_atomic_kernel(
    const float* __restrict__ h, const unsigned short* __restrict__ W1TF,
    const float* __restrict__ b1, const float* __restrict__ W2,
    const int* __restrict__ batch, float* __restrict__ outnum,
    float* __restrict__ den, int N) {
    __shared__ unsigned short hA[BM * D_DIM];
    __shared__ float plds[4][BM];
    __shared__ float wl[BM];
    __shared__ int gb[BM];

    const int tid = threadIdx.x;
    const int lane = tid & 63;
    const int w = tid >> 6;
    const int cg = lane & 15;
    const int qg = lane >> 4;
    const int row0 = blockIdx.x * BM;

    if (tid < BM) {
        int gr = row0 + tid;
        gb[tid] = batch[gr < N ? gr : N - 1];
    }
#pragma unroll
    for (int b = 0; b < 4; ++b) {
        float4 fa[4], fb[4];
#pragma unroll
        for (int i = 0; i < 4; ++i) {
            const int fi = (b * 4 + i) * 256 + tid;
            const int r = fi >> 6, u = fi & 63;
            int gr = row0 + r;
            gr = gr < N ? gr : N - 1;
            const float* p = h + (size_t)gr * D_DIM + u * 8;
            fa[i] = *(const float4*)p;
            fb[i] = *(const float4*)(p + 4);
        }
#pragma unroll
        for (int i = 0; i < 4; ++i) {
            const int fi = (b * 4 + i) * 256 + tid;
            const int r = fi >> 6, u = fi & 63;
            uint4 val;
            val.x = pack_bf2(fa[i].x, fa[i].y);
            val.y = pack_bf2(fa[i].z, fa[i].w);
            val.z = pack_bf2(fb[i].x, fb[i].y);
            val.w = pack_bf2(fb[i].z, fb[i].w);
            *(uint4*)&hA[r * D_DIM + ((u ^ (r & 7)) * 8)] = val;
        }
    }
    __syncthreads();

    f32x4 acc[4][2];
#pragma unroll
    for (int rf = 0; rf < 4; ++rf)
#pragma unroll
        for (int cf = 0; cf < 2; ++cf) acc[rf][cf] = (f32x4){0.f, 0.f, 0.f, 0.f};
#pragma unroll
    for (int ki = 0; ki < 16; ++ki) {
        short8 bfg[2];
#pragma unroll
        for (int cf = 0; cf < 2; ++cf)
            bfg[cf] = *(const short8*)(W1TF + (((w * 2 + cf) * 16 + ki) << 9) + lane * 8);
#pragma unroll
        for (int rf = 0; rf < 4; ++rf) {
            const int row = rf * 16 + cg;
            const short8 af = *(const short8*)&hA[row * D_DIM +
                (((4 * ki + qg) ^ (row & 7)) * 8)];
#pragma unroll
            for (int cf = 0; cf < 2; ++cf)
                acc[rf][cf] = __builtin_amdgcn_mfma_f32_16x16x32_bf16(
                    af, bfg[cf], acc[rf][cf], 0, 0, 0);
        }
    }
    const float b1v0 = b1[w * 32 + cg];
    const float b1v1 = b1[w * 32 + 16 + cg];
    const float w2v0 = W2[w * 32 + cg];
    const float w2v1 = W2[w * 32 + 16 + cg];
#pragma unroll
    for (int rf = 0; rf < 4; ++rf) {
#pragma unroll
        for (int reg = 0; reg < 4; ++reg) {
            float p = fast_tanh(acc[rf][0][reg] + b1v0) * w2v0 +
                      fast_tanh(acc[rf][1][reg] + b1v1) * w2v1;
#pragma unroll
            for (int o = 1; o < 16; o <<= 1) p += __shfl_xor(p, o, 64);
            if (cg == 0) plds[w][rf * 16 + qg * 4 + reg] = p;
        }
    }
    __syncthreads();
    if (tid < BM) {
        const float l = plds[0][tid] + plds[1][tid] + plds[2][tid] + plds[3][tid];
        wl[tid] = (row0 + tid < N) ? __expf(fminf(l, 60.f)) : 0.f;
    }
    __syncthreads();

    const int d0 = (tid >> 2) * 8 + (tid & 3) * 2;
    float ax = 0.f, ay = 0.f;
    int cur = gb[0];
#pragma unroll 8
    for (int j = 0; j < BM; ++j) {
        const int gj = gb[j];
        if (gj != cur) {
            atomicAdd(&outnum[(size_t)cur * D_DIM + d0], ax);
            atomicAdd(&outnum[(size_t)cur * D_DIM + d0 + 1], ay);
            ax = 0.f; ay = 0.f; cur = gj;
        }
        const float wj = wl[j];
        const unsigned int pair = *(const unsigned int*)&hA[j * D_DIM +
            (((tid >> 2) ^ (j & 7)) * 8) + (tid & 3) * 2];
        ax += wj * __uint_as_float(pair << 16);
        ay += wj * __uint_as_float(pair & 0xffff0000u);
    }
    atomicAdd(&outnum[(size_t)cur * D_DIM + d0], ax);
    atomicAdd(&outnum[(size_t)cur * D_DIM + d0 + 1], ay);

    if (tid == 0) {
        float a = 0.f;
        int c2 = gb[0];
        for (int j = 0; j < BM; ++j) {
            if (gb[j] != c2) { atomicAdd(&den[c2], a); a = 0.f; c2 = gb[j]; }
            a += wl[j];
        }
        atomicAdd(&den[c2], a);
    }
}

__global__ __launch_bounds__(512) void finalize_kernel(
    float* __restrict__ out, const float* __restrict__ den) {
    const int g = blockIdx.x;
    const float dv = den[g];
    const float v = out[(size_t)g * D_DIM + threadIdx.x];
    out[(size_t)g * D_DIM + threadIdx.x] = dv > 0.f ? v / dv : 0.f;
}

extern "C" void kernel_launch(void* const* d_in, const int* in_sizes, int n_in,
                              void* d_out, int out_size, void* d_ws, size_t ws_size,
                              hipStream_t stream) {
    const float* h = (const float*)d_in[0];
    const int* batch = (const int*)d_in[1];
    const float* W1 = (const float*)d_in[2];
    const float* b1 = (const float*)d_in[3];
    const float* W2 = (const float*)d_in[4];
    // b2 unused: constant shift cancels in segment softmax
    float* out = (float*)d_out;
    const int N = in_sizes[1];
    const int NB = (N + BM - 1) / BM;

    char* ws = (char*)d_ws;
    int* off = (int*)ws;                                  // 4100 B
    unsigned short* W1TF = (unsigned short*)(ws + 4608);  // 131072 B
    float* P = (float*)(ws + 135680);                     // NB*2*513 floats

    const size_t need = 135680 + (size_t)NB * 2 * 513 * 4;

    seg_offsets_kernel<<<(NGRAPHS + 256) / 256 + 1, 256, 0, stream>>>(batch, N, off);
    prep_w1t_kernel<<<(D_DIM * H_DIM) / 256, 256, 0, stream>>>(W1, W1TF);

    if (ws_size >= need) {
        gate_pool_partial_kernel<<<NB, 512, 0, stream>>>(h, W1TF, b1, W2, batch,
                                                         P, out, N);
        reduce_kernel<<<NGRAPHS, 512, 0, stream>>>(P, off, batch, out, N);
    } else {
        float* den = P;  // 4 KB
        zero_kernel<<<(NGRAPHS * D_DIM + 255) / 256, 256, 0, stream>>>(out, den);
        gate_pool_atomic_kernel<<<NB, 256, 0, stream>>>(h, W1TF, b1, W2, batch,
                                                        out, den, N);
        finalize_kernel<<<NGRAPHS, 512, 0, stream>>>(out, den);
    }
}

// Round 14
// 137.640 us; speedup vs baseline: 2.0255x; 1.1306x over previous
//
#include <hip/hip_runtime.h>
#include <hip/hip_bf16.h>

typedef __attribute__((ext_vector_type(8))) short short8;
typedef __attribute__((ext_vector_type(4))) float f32x4;

#define NGRAPHS 1024
#define D_DIM 512
#define H_DIM 128
#define BM 64  // rows per block

// standard RNE f32->bf16 pair pack; compiler lowers to v_cvt_pk_bf16_f32
static __device__ __forceinline__ unsigned int pack_bf2(float a, float b) {
    float2 t; t.x = a; t.y = b;
    __hip_bfloat162 h = __float22bfloat162_rn(t);
    union { __hip_bfloat162 h; unsigned int u; } v;
    v.h = h;
    return v.u;
}

static __device__ __forceinline__ unsigned short f2bf(float f) {
    __hip_bfloat16 h = __float2bfloat16(f);
    union { __hip_bfloat16 h; unsigned short u; } v;
    v.h = h;
    return v.u;
}

static __device__ __forceinline__ float fast_tanh(float x) {
    float cx = fminf(fmaxf(x, -15.f), 15.f);
    float e = __expf(2.f * cx);
    return (e - 1.f) / (e + 1.f);
}

// ---------------- segment offsets via binary search ----------------
__global__ void seg_offsets_kernel(const int* __restrict__ batch, int N,
                                   int* __restrict__ off) {
    int g = blockIdx.x * 256 + threadIdx.x;
    if (g > NGRAPHS) return;
    int lo = 0, hi = N;
    while (lo < hi) {
        int mid = (lo + hi) >> 1;
        if (batch[mid] < g) lo = mid + 1;
        else hi = mid;
    }
    off[g] = lo;
}

// ---- W1 [512][128] f32 -> fragment-major bf16 W1TF ----
// W1TF[cgrp][ki][lane][e]: col = cgrp*16 + (lane&15), k = ki*32 + (lane>>4)*8 + e.
__global__ void prep_w1t_kernel(const float* __restrict__ W1,
                                unsigned short* __restrict__ W1TF) {
    int idx = blockIdx.x * 256 + threadIdx.x;  // 0..65535
    int e = idx & 7;
    int lane = (idx >> 3) & 63;
    int ki = (idx >> 9) & 15;
    int cgrp = idx >> 13;  // 0..7
    int col = cgrp * 16 + (lane & 15);
    int k = ki * 32 + (lane >> 4) * 8 + e;
    W1TF[idx] = f2bf(W1[k * H_DIM + col]);
}

// =================== PARTIAL-STORE PATH (no atomics) ===================
// 256 threads (4 waves), 64 rows/block. Wave w owns gate cols [w*32, w*32+32)
// (bfr[2][16] = 128 VGPR). SWAPPED-operand MFMA: acc = mfma(bfr, af) puts
// row = rf*16 + (lane&15), col = w*32+cf*16+qg*4+reg -> epilogue reduce is
// in-thread 8-sum + 2 shfl_xor (o=16,32), cutting DS-pipe work ~4x vs R9.
// exp() without max-subtraction is safe: |logit| <= ||W2||_1 ~ 9; b2 cancels.
// Each block writes <=2 boundary partial records P[b][slot][513]; interior
// graphs final-written. reduce_kernel combines boundary partials.
__global__ __launch_bounds__(256, 2) void gate_pool_partial_kernel(
    const float* __restrict__ h, const unsigned short* __restrict__ W1TF,
    const float* __restrict__ b1, const float* __restrict__ W2,
    const int* __restrict__ batch, float* __restrict__ P,
    float* __restrict__ out, int N) {
    __shared__ unsigned short hA[BM * D_DIM];  // 64 KB, XOR-swizzled 16B units
    __shared__ float plds[4][BM];
    __shared__ float wl[BM];
    __shared__ int gb[BM];

    const int tid = threadIdx.x;
    const int lane = tid & 63;
    const int w = tid >> 6;      // wave 0..3
    const int cg = lane & 15;
    const int qg = lane >> 4;
    const int row0 = blockIdx.x * BM;

    if (tid < BM) {
        int gr = row0 + tid;
        gb[tid] = batch[gr < N ? gr : N - 1];
    }

    // ---- stage h -> bf16 LDS. 128 (row,half) 1KB tasks, 32 per thread,
    // two 16-load batches (64 transient VGPR each).
#pragma unroll
    for (int bb = 0; bb < 2; ++bb) {
        float4 f[16];
#pragma unroll
        for (int i = 0; i < 16; ++i) {
            const int task = (bb * 16 + i) * 4 + w;
            const int row = task >> 1, half = task & 1;
            int gr = row0 + row;
            gr = gr < N ? gr : N - 1;
            f[i] = *(const float4*)(h + (size_t)gr * D_DIM + half * 256 + lane * 4);
        }
        __builtin_amdgcn_sched_barrier(0);  // keep loads above the packs
#pragma unroll
        for (int i = 0; i < 16; ++i) {
            const int task = (bb * 16 + i) * 4 + w;
            const int row = task >> 1, half = task & 1;
            const int unit = half * 32 + (lane >> 1);
            uint2 v;
            v.x = pack_bf2(f[i].x, f[i].y);
            v.y = pack_bf2(f[i].z, f[i].w);
            *(uint2*)&hA[row * D_DIM + ((unit ^ (row & 7)) * 8) + (lane & 1) * 4] = v;
        }
    }

    // B fragments into registers while staging drains (L2-hot): 32 cols/wave
    short8 bfr[2][16];
#pragma unroll
    for (int cf = 0; cf < 2; ++cf)
#pragma unroll
        for (int ki = 0; ki < 16; ++ki)
            bfr[cf][ki] = *(const short8*)(W1TF +
                (((w * 2 + cf) * 16 + ki) << 9) + lane * 8);
    __syncthreads();

    // ---- gate MLP (swapped operands): 64 rows x 32 cols per wave, K=512 ----
    f32x4 acc[4][2];
#pragma unroll
    for (int rf = 0; rf < 4; ++rf)
#pragma unroll
        for (int cf = 0; cf < 2; ++cf) acc[rf][cf] = (f32x4){0.f, 0.f, 0.f, 0.f};
#pragma unroll
    for (int ki = 0; ki < 16; ++ki) {
#pragma unroll
        for (int rf = 0; rf < 4; ++rf) {
            const short8 af = *(const short8*)&hA[(rf * 16 + cg) * D_DIM +
                (((4 * ki + qg) ^ (cg & 7)) * 8)];
#pragma unroll
            for (int cf = 0; cf < 2; ++cf)
                acc[rf][cf] = __builtin_amdgcn_mfma_f32_16x16x32_bf16(
                    bfr[cf][ki], af, acc[rf][cf], 0, 0, 0);
        }
    }

    // ---- epilogue: thread holds cols w*32+cf*16+qg*4+reg for row rf*16+cg ----
    float4 b1v[2], w2v[2];
#pragma unroll
    for (int cf = 0; cf < 2; ++cf) {
        b1v[cf] = *(const float4*)&b1[w * 32 + cf * 16 + qg * 4];
        w2v[cf] = *(const float4*)&W2[w * 32 + cf * 16 + qg * 4];
    }
#pragma unroll
    for (int rf = 0; rf < 4; ++rf) {
        float p = 0.f;
#pragma unroll
        for (int cf = 0; cf < 2; ++cf) {
            p += fast_tanh(acc[rf][cf][0] + b1v[cf].x) * w2v[cf].x;
            p += fast_tanh(acc[rf][cf][1] + b1v[cf].y) * w2v[cf].y;
            p += fast_tanh(acc[rf][cf][2] + b1v[cf].z) * w2v[cf].z;
            p += fast_tanh(acc[rf][cf][3] + b1v[cf].w) * w2v[cf].w;
        }
        p += __shfl_xor(p, 16, 64);
        p += __shfl_xor(p, 32, 64);
        if (qg == 0) plds[w][rf * 16 + cg] = p;
    }
    __syncthreads();

    if (tid < BM) {
        const float l = plds[0][tid] + plds[1][tid] + plds[2][tid] + plds[3][tid];
        wl[tid] = (row0 + tid < N) ? __expf(fminf(l, 60.f)) : 0.f;
    }
    __syncthreads();

    // ---- pooling + segment flushes: 256 threads, thread owns dims d0,d0+1 ----
    {
        const int d0 = (tid >> 2) * 8 + (tid & 3) * 2;
        float ax = 0.f, ay = 0.f, d = 0.f;
        int curg = gb[0];
#pragma unroll 8
        for (int j = 0; j < BM; ++j) {
            const int gj = gb[j];
            if (gj != curg) {  // block-uniform branch
                if (curg == gb[0]) {
                    float* rec = P + (size_t)blockIdx.x * 2 * 513;
                    rec[d0] = ax; rec[d0 + 1] = ay;
                    if (tid == 0) rec[512] = d;
                } else {  // interior graph: exclusive owner -> final write
                    out[(size_t)curg * D_DIM + d0] = ax / d;
                    out[(size_t)curg * D_DIM + d0 + 1] = ay / d;
                }
                ax = 0.f; ay = 0.f; d = 0.f; curg = gj;
            }
            const float wj = wl[j];
            const unsigned int pair = *(const unsigned int*)&hA[j * D_DIM +
                (((tid >> 2) ^ (j & 7)) * 8) + (tid & 3) * 2];
            ax += wj * __uint_as_float(pair << 16);
            ay += wj * __uint_as_float(pair & 0xffff0000u);
            d += wj;
        }
        const int slot = (curg == gb[0]) ? 0 : 1;
        float* rec = P + ((size_t)blockIdx.x * 2 + slot) * 513;
        rec[d0] = ax; rec[d0 + 1] = ay;
        if (tid == 0) rec[512] = d;
        if (gb[0] == gb[BM - 1]) {  // slot1 unused -> zero for determinism
            float* r1 = P + ((size_t)blockIdx.x * 2 + 1) * 513;
            r1[d0] = 0.f; r1[d0 + 1] = 0.f;
            if (tid == 0) r1[512] = 0.f;
        }
    }
}

// combine boundary partials; skip interior graphs (already final-written)
__global__ __launch_bounds__(512) void reduce_kernel(
    const float* __restrict__ P, const int* __restrict__ off,
    const int* __restrict__ batch, float* __restrict__ out, int N) {
    const int g = blockIdx.x;
    const int tid = threadIdx.x;
    const int s = off[g], e = off[g + 1];
    if (e <= s) { out[(size_t)g * D_DIM + tid] = 0.f; return; }
    const int t0 = s >> 6, t1 = (e - 1) >> 6;
    float sum = 0.f, den = 0.f;
    bool found = false;
    for (int b = t0; b <= t1; ++b) {
        const int fg = batch[b << 6];
        const int le = (b << 6) + 63;
        const int lg = batch[le < N ? le : N - 1];
        if (fg == g) {
            const float* rec = P + (size_t)b * 2 * 513;
            sum += rec[tid]; den += rec[512]; found = true;
        } else if (lg == g) {
            const float* rec = P + ((size_t)b * 2 + 1) * 513;
            sum += rec[tid]; den += rec[512]; found = true;
        }
    }
    if (found) out[(size_t)g * D_DIM + tid] = sum / den;
}

// =================== ATOMIC FALLBACK (R8/R9, proven) ===================
__global__ void zero_kernel(float* __restrict__ out, float* __restrict__ den) {
    int i = blockIdx.x * 256 + threadIdx.x;
    if (i < NGRAPHS * D_DIM) out[i] = 0.f;
    if (i < NGRAPHS) den[i] = 0.f;
}

__global__ __launch_bounds__(256) void gate_pool_atomic_kernel(
    const float* __restrict__ h, const unsigned short* __restrict__ W1TF,
    const float* __restrict__ b1, const float* __restrict__ W2,
    const int* __restrict__ batch, float* __restrict__ outnum,
    float* __restrict__ den, int N) {
    __shared__ unsigned short hA[BM * D_DIM];
    __shared__ float plds[4][BM];
    __shared__ float wl[BM];
    __shared__ int gb[BM];

    const int tid = threadIdx.x;
    const int lane = tid & 63;
    const int w = tid >> 6;
    const int cg = lane & 15;
    const int qg = lane >> 4;
    const int row0 = blockIdx.x * BM;

    if (tid < BM) {
        int gr = row0 + tid;
        gb[tid] = batch[gr < N ? gr : N - 1];
    }
#pragma unroll
    for (int b = 0; b < 4; ++b) {
        float4 fa[4], fb[4];
#pragma unroll
        for (int i = 0; i < 4; ++i) {
            const int fi = (b * 4 + i) * 256 + tid;
            const int r = fi >> 6, u = fi & 63;
            int gr = row0 + r;
            gr = gr < N ? gr : N - 1;
            const float* p = h + (size_t)gr * D_DIM + u * 8;
            fa[i] = *(const float4*)p;
            fb[i] = *(const float4*)(p + 4);
        }
#pragma unroll
        for (int i = 0; i < 4; ++i) {
            const int fi = (b * 4 + i) * 256 + tid;
            const int r = fi >> 6, u = fi & 63;
            uint4 val;
            val.x = pack_bf2(fa[i].x, fa[i].y);
            val.y = pack_bf2(fa[i].z, fa[i].w);
            val.z = pack_bf2(fb[i].x, fb[i].y);
            val.w = pack_bf2(fb[i].z, fb[i].w);
            *(uint4*)&hA[r * D_DIM + ((u ^ (r & 7)) * 8)] = val;
        }
    }
    __syncthreads();

    f32x4 acc[4][2];
#pragma unroll
    for (int rf = 0; rf < 4; ++rf)
#pragma unroll
        for (int cf = 0; cf < 2; ++cf) acc[rf][cf] = (f32x4){0.f, 0.f, 0.f, 0.f};
#pragma unroll
    for (int ki = 0; ki < 16; ++ki) {
        short8 bfg[2];
#pragma unroll
        for (int cf = 0; cf < 2; ++cf)
            bfg[cf] = *(const short8*)(W1TF + (((w * 2 + cf) * 16 + ki) << 9) + lane * 8);
#pragma unroll
        for (int rf = 0; rf < 4; ++rf) {
            const int row = rf * 16 + cg;
            const short8 af = *(const short8*)&hA[row * D_DIM +
                (((4 * ki + qg) ^ (row & 7)) * 8)];
#pragma unroll
            for (int cf = 0; cf < 2; ++cf)
                acc[rf][cf] = __builtin_amdgcn_mfma_f32_16x16x32_bf16(
                    af, bfg[cf], acc[rf][cf], 0, 0, 0);
        }
    }
    const float b1v0 = b1[w * 32 + cg];
    const float b1v1 = b1[w * 32 + 16 + cg];
    const float w2v0 = W2[w * 32 + cg];
    const float w2v1 = W2[w * 32 + 16 + cg];
#pragma unroll
    for (int rf = 0; rf < 4; ++rf) {
#pragma unroll
        for (int reg = 0; reg < 4; ++reg) {
            float p = fast_tanh(acc[rf][0][reg] + b1v0) * w2v0 +
                      fast_tanh(acc[rf][1][reg] + b1v1) * w2v1;
#pragma unroll
            for (int o = 1; o < 16; o <<= 1) p += __shfl_xor(p, o, 64);
            if (cg == 0) plds[w][rf * 16 + qg * 4 + reg] = p;
        }
    }
    __syncthreads();
    if (tid < BM) {
        const float l = plds[0][tid] + plds[1][tid] + plds[2][tid] + plds[3][tid];
        wl[tid] = (row0 + tid < N) ? __expf(fminf(l, 60.f)) : 0.f;
    }
    __syncthreads();

    const int d0 = (tid >> 2) * 8 + (tid & 3) * 2;
    float ax = 0.f, ay = 0.f;
    int cur = gb[0];
#pragma unroll 8
    for (int j = 0; j < BM; ++j) {
        const int gj = gb[j];
        if (gj != cur) {
            atomicAdd(&outnum[(size_t)cur * D_DIM + d0], ax);
            atomicAdd(&outnum[(size_t)cur * D_DIM + d0 + 1], ay);
            ax = 0.f; ay = 0.f; cur = gj;
        }
        const float wj = wl[j];
        const unsigned int pair = *(const unsigned int*)&hA[j * D_DIM +
            (((tid >> 2) ^ (j & 7)) * 8) + (tid & 3) * 2];
        ax += wj * __uint_as_float(pair << 16);
        ay += wj * __uint_as_float(pair & 0xffff0000u);
    }
    atomicAdd(&outnum[(size_t)cur * D_DIM + d0], ax);
    atomicAdd(&outnum[(size_t)cur * D_DIM + d0 + 1], ay);

    if (tid == 0) {
        float a = 0.f;
        int c2 = gb[0];
        for (int j = 0; j < BM; ++j) {
            if (gb[j] != c2) { atomicAdd(&den[c2], a); a = 0.f; c2 = gb[j]; }
            a += wl[j];
        }
        atomicAdd(&den[c2], a);
    }
}

__global__ __launch_bounds__(512) void finalize_kernel(
    float* __restrict__ out, const float* __restrict__ den) {
    const int g = blockIdx.x;
    const float dv = den[g];
    const float v = out[(size_t)g * D_DIM + threadIdx.x];
    out[(size_t)g * D_DIM + threadIdx.x] = dv > 0.f ? v / dv : 0.f;
}

extern "C" void kernel_launch(void* const* d_in, const int* in_sizes, int n_in,
                              void* d_out, int out_size, void* d_ws, size_t ws_size,
                              hipStream_t stream) {
    const float* h = (const float*)d_in[0];
    const int* batch = (const int*)d_in[1];
    const float* W1 = (const float*)d_in[2];
    const float* b1 = (const float*)d_in[3];
    const float* W2 = (const float*)d_in[4];
    // b2 unused: constant shift cancels in segment softmax
    float* out = (float*)d_out;
    const int N = in_sizes[1];
    const int NB = (N + BM - 1) / BM;

    char* ws = (char*)d_ws;
    int* off = (int*)ws;                                  // 4100 B
    unsigned short* W1TF = (unsigned short*)(ws + 4608);  // 131072 B
    float* P = (float*)(ws + 135680);                     // NB*2*513 floats

    const size_t need = 135680 + (size_t)NB * 2 * 513 * 4;

    seg_offsets_kernel<<<(NGRAPHS + 256) / 256 + 1, 256, 0, stream>>>(batch, N, off);
    prep_w1t_kernel<<<(D_DIM * H_DIM) / 256, 256, 0, stream>>>(W1, W1TF);

    if (ws_size >= need) {
        gate_pool_partial_kernel<<<NB, 256, 0, stream>>>(h, W1TF, b1, W2, batch,
                                                         P, out, N);
        reduce_kernel<<<NGRAPHS, 512, 0, stream>>>(P, off, batch, out, N);
    } else {
        float* den = P;  // 4 KB
        zero_kernel<<<(NGRAPHS * D_DIM + 255) / 256, 256, 0, stream>>>(out, den);
        gate_pool_atomic_kernel<<<NB, 256, 0, stream>>>(h, W1TF, b1, W2, batch,
                                                        out, den, N);
        finalize_kernel<<<NGRAPHS, 512, 0, stream>>>(out, den);
    }
}